// Round 1
// baseline (5672.051 us; speedup 1.0000x reference)
//
#include <hip/hip_runtime.h>
#include <math.h>

#define LNUM 6
#define HNUM 12
#define CDIM 768
#define VDIM 50257
#define BDIM 4
#define TDIM 1024
#define HD 64
#define NTOK 4096   // B*T

typedef __bf16 bf16;
typedef __bf16 bf16x8 __attribute__((ext_vector_type(8)));
typedef float  floatx4 __attribute__((ext_vector_type(4)));

// ---------------- fp32 -> bf16 bulk convert (wte) ----------------
__global__ void k_cvt_bf16(const float* __restrict__ in, bf16* __restrict__ out, long n) {
  long i = ((long)blockIdx.x * blockDim.x + threadIdx.x) * 4;
  long stride = (long)gridDim.x * blockDim.x * 4;
  for (; i < n; i += stride) {
    float4 v = *reinterpret_cast<const float4*>(in + i);
    bf16 b0 = (bf16)v.x, b1 = (bf16)v.y, b2 = (bf16)v.z, b3 = (bf16)v.w;
    ushort4 pk;
    pk.x = __builtin_bit_cast(unsigned short, b0);
    pk.y = __builtin_bit_cast(unsigned short, b1);
    pk.z = __builtin_bit_cast(unsigned short, b2);
    pk.w = __builtin_bit_cast(unsigned short, b3);
    *reinterpret_cast<ushort4*>(out + i) = pk;
  }
}

// ---------------- transpose + convert: in fp32 [K,N] -> out bf16 [N,K] ----------------
// K, N multiples of 32.
__global__ void k_transpose_cvt(const float* __restrict__ in, bf16* __restrict__ out, int K, int N) {
  __shared__ float tile[32][33];
  int n0 = blockIdx.x * 32, k0 = blockIdx.y * 32;
  int nx = threadIdx.x & 31, ty = threadIdx.x >> 5;
  #pragma unroll
  for (int p = 0; p < 4; ++p) {
    int k = ty + p * 8;
    tile[k][nx] = in[(size_t)(k0 + k) * N + n0 + nx];
  }
  __syncthreads();
  #pragma unroll
  for (int p = 0; p < 4; ++p) {
    int n = ty + p * 8;
    out[(size_t)(n0 + n) * K + k0 + nx] = (bf16)tile[nx][n];
  }
}

// ---------------- embedding: x = wte[idx] + wpe[t] ----------------
__global__ void k_embed(const int* __restrict__ idx, const float* __restrict__ wte,
                        const float* __restrict__ wpe, float* __restrict__ x) {
  int tok = blockIdx.x;
  int t = tok & (TDIM - 1);
  int id = idx[tok];
  const float* a = wte + (size_t)id * CDIM;
  const float* p = wpe + (size_t)t * CDIM;
  float* o = x + (size_t)tok * CDIM;
  for (int c = threadIdx.x; c < CDIM; c += 256) o[c] = a[c] + p[c];
}

// ---------------- layernorm: fp32 in -> bf16 out ----------------
__global__ __launch_bounds__(256) void k_layernorm(const float* __restrict__ x,
    const float* __restrict__ sc, const float* __restrict__ bi, bf16* __restrict__ out) {
  __shared__ float red[8];
  int row = blockIdx.x;
  const float* xr = x + (size_t)row * CDIM;
  int t = threadIdx.x;
  float v0 = xr[t], v1 = xr[t + 256], v2 = xr[t + 512];
  float s = v0 + v1 + v2;
  #pragma unroll
  for (int o = 32; o > 0; o >>= 1) s += __shfl_down(s, o);
  if ((t & 63) == 0) red[t >> 6] = s;
  __syncthreads();
  float mean = (red[0] + red[1] + red[2] + red[3]) * (1.0f / CDIM);
  float d0 = v0 - mean, d1 = v1 - mean, d2 = v2 - mean;
  float q = d0 * d0 + d1 * d1 + d2 * d2;
  #pragma unroll
  for (int o = 32; o > 0; o >>= 1) q += __shfl_down(q, o);
  if ((t & 63) == 0) red[4 + (t >> 6)] = q;
  __syncthreads();
  float var = (red[4] + red[5] + red[6] + red[7]) * (1.0f / CDIM);
  float rs = rsqrtf(var + 1e-5f);
  bf16* orow = out + (size_t)row * CDIM;
  orow[t]       = (bf16)(d0 * rs * sc[t]       + bi[t]);
  orow[t + 256] = (bf16)(d1 * rs * sc[t + 256] + bi[t + 256]);
  orow[t + 512] = (bf16)(d2 * rs * sc[t + 512] + bi[t + 512]);
}

// ---------------- NT bf16 MFMA GEMM: C[M,N] = A[M,K] * Bt[N,K]^T ----------------
// BM=BN=128, BK=64, 256 threads (4 waves in 2x2), each wave 64x64 = 4x4 frags of 16x16.
// EPI: 0 = ->f32, 1 = +bias ->f32, 2 = +bias+resid ->f32 (in-place residual),
//      3 = +bias+gelu ->bf16
#define BM 128
#define BN 128
#define BKK 64
#define LDSS 72   // LDS row stride in bf16 (144B, 16B-aligned, optimal b128 banking)

__device__ inline float gelu_f(float x) {
  float x3 = x * x * x;
  return 0.5f * x * (1.0f + tanhf(0.7978845608028654f * (x + 0.044715f * x3)));
}

template<int EPI>
__global__ __launch_bounds__(256) void k_gemm_nt(
    const bf16* __restrict__ A, const bf16* __restrict__ Bt,
    const float* __restrict__ bias, const float* __restrict__ resid,
    float* __restrict__ Cf, bf16* __restrict__ Cb,
    int M, int N, int K) {
  __shared__ __align__(16) bf16 As[BM * LDSS];
  __shared__ __align__(16) bf16 Bs[BN * LDSS];
  int m0 = blockIdx.x * BM, n0 = blockIdx.y * BN;
  int tid = threadIdx.x;
  int lane = tid & 63, wave = tid >> 6;
  int wr = wave >> 1, wc = wave & 1;

  floatx4 acc[4][4] = {};

  int srow = tid >> 3;   // 0..31, 4 passes cover 128 rows
  int sseg = tid & 7;    // 8 x 8bf16 segments per 64-wide K chunk

  const bf16* pa_base = As + ((wr * 64) + (lane & 15)) * LDSS + (lane >> 4) * 8;
  const bf16* pb_base = Bs + ((wc * 64) + (lane & 15)) * LDSS + (lane >> 4) * 8;

  for (int k0 = 0; k0 < K; k0 += BKK) {
    #pragma unroll
    for (int i = 0; i < 4; ++i) {
      int row = srow + i * 32;
      uint4 av = *reinterpret_cast<const uint4*>(A + (size_t)(m0 + row) * K + k0 + sseg * 8);
      *reinterpret_cast<uint4*>(&As[row * LDSS + sseg * 8]) = av;
      int nrow = n0 + row;
      uint4 bv = {0u, 0u, 0u, 0u};
      if (nrow < N) bv = *reinterpret_cast<const uint4*>(Bt + (size_t)nrow * K + k0 + sseg * 8);
      *reinterpret_cast<uint4*>(&Bs[row * LDSS + sseg * 8]) = bv;
    }
    __syncthreads();
    #pragma unroll
    for (int kk = 0; kk < 2; ++kk) {
      bf16x8 af[4], bfr[4];
      #pragma unroll
      for (int i = 0; i < 4; ++i)
        af[i] = *reinterpret_cast<const bf16x8*>(pa_base + i * 16 * LDSS + kk * 32);
      #pragma unroll
      for (int j = 0; j < 4; ++j)
        bfr[j] = *reinterpret_cast<const bf16x8*>(pb_base + j * 16 * LDSS + kk * 32);
      #pragma unroll
      for (int i = 0; i < 4; ++i) {
        #pragma unroll
        for (int j = 0; j < 4; ++j)
          acc[i][j] = __builtin_amdgcn_mfma_f32_16x16x32_bf16(af[i], bfr[j], acc[i][j], 0, 0, 0);
      }
    }
    __syncthreads();
  }

  // C/D layout (verified, m89/m91): col = lane&15, row = (lane>>4)*4 + reg
  int mb = m0 + wr * 64 + (lane >> 4) * 4;
  int nb = n0 + wc * 64 + (lane & 15);
  #pragma unroll
  for (int j = 0; j < 4; ++j) {
    int n = nb + j * 16;
    if (n >= N) continue;
    float bv = (EPI >= 1) ? bias[n] : 0.0f;
    #pragma unroll
    for (int i = 0; i < 4; ++i) {
      #pragma unroll
      for (int q = 0; q < 4; ++q) {
        int m = mb + i * 16 + q;
        float v = acc[i][j][q] + bv;
        size_t o = (size_t)m * N + n;
        if (EPI == 2)      Cf[o] = v + resid[o];
        else if (EPI == 3) Cb[o] = (bf16)gelu_f(v);
        else               Cf[o] = v;
      }
    }
  }
}

// ---------------- causal attention (fp32, flash-style online softmax) ----------------
// grid (B*H, T/64); block 256 (4 waves); wave handles 16 q rows; lane = k (scores) / d (PV).
__global__ __launch_bounds__(256) void k_attn(const float* __restrict__ qkv, bf16* __restrict__ y) {
  __shared__ float Qs[64 * 68];
  __shared__ float Ks[64 * 68];
  __shared__ float Vs[64 * 68];
  int bh = blockIdx.x;
  int b = bh / HNUM, h = bh % HNUM;
  int qt = blockIdx.y;
  int lane = threadIdx.x & 63, wave = threadIdx.x >> 6;
  int w16 = wave * 16;

  {  // stage Q tile
    int r = threadIdx.x >> 2, s4 = threadIdx.x & 3;
    const float* src = qkv + (size_t)(b * TDIM + qt * 64 + r) * (3 * CDIM) + h * HD;
    #pragma unroll
    for (int j = 0; j < 4; ++j) {
      int d = (j * 4 + s4) * 4;
      *reinterpret_cast<float4*>(&Qs[r * 68 + d]) = *reinterpret_cast<const float4*>(src + d);
    }
  }

  float m_r[16], l_r[16], o_r[16];
  #pragma unroll
  for (int r = 0; r < 16; ++r) { m_r[r] = -1e30f; l_r[r] = 0.f; o_r[r] = 0.f; }

  for (int kt = 0; kt <= qt; ++kt) {
    __syncthreads();
    {  // stage K,V tile
      int r = threadIdx.x >> 2, s4 = threadIdx.x & 3;
      const float* srck = qkv + (size_t)(b * TDIM + kt * 64 + r) * (3 * CDIM) + CDIM + h * HD;
      const float* srcv = srck + CDIM;
      #pragma unroll
      for (int j = 0; j < 4; ++j) {
        int d = (j * 4 + s4) * 4;
        *reinterpret_cast<float4*>(&Ks[r * 68 + d]) = *reinterpret_cast<const float4*>(srck + d);
        *reinterpret_cast<float4*>(&Vs[r * 68 + d]) = *reinterpret_cast<const float4*>(srcv + d);
      }
    }
    __syncthreads();

    bool diag = (kt == qt);
    float s_r[16];
    #pragma unroll
    for (int r = 0; r < 16; ++r) s_r[r] = 0.f;
    #pragma unroll 4
    for (int d4 = 0; d4 < 16; ++d4) {
      float4 kv = *reinterpret_cast<const float4*>(&Ks[lane * 68 + d4 * 4]);
      #pragma unroll
      for (int r = 0; r < 16; ++r) {
        float4 qv = *reinterpret_cast<const float4*>(&Qs[(w16 + r) * 68 + d4 * 4]);
        s_r[r] = fmaf(qv.x, kv.x, s_r[r]);
        s_r[r] = fmaf(qv.y, kv.y, s_r[r]);
        s_r[r] = fmaf(qv.z, kv.z, s_r[r]);
        s_r[r] = fmaf(qv.w, kv.w, s_r[r]);
      }
    }
    float p_r[16];
    #pragma unroll
    for (int r = 0; r < 16; ++r) {
      float s = s_r[r] * 0.125f;                 // 1/sqrt(HD)
      if (diag && lane > w16 + r) s = -1e30f;    // causal mask within diagonal tile
      float mx = s;
      #pragma unroll
      for (int o = 32; o > 0; o >>= 1) mx = fmaxf(mx, __shfl_xor(mx, o));
      float mnew = fmaxf(m_r[r], mx);
      float p = __expf(s - mnew);
      float ps = p;
      #pragma unroll
      for (int o = 32; o > 0; o >>= 1) ps += __shfl_xor(ps, o);
      float alpha = __expf(m_r[r] - mnew);
      m_r[r] = mnew;
      l_r[r] = l_r[r] * alpha + ps;
      o_r[r] *= alpha;
      p_r[r] = p;
    }
    #pragma unroll 4
    for (int k = 0; k < 64; ++k) {
      float vkd = Vs[k * 68 + lane];
      #pragma unroll
      for (int r = 0; r < 16; ++r) {
        float pk = __shfl(p_r[r], k);
        o_r[r] = fmaf(pk, vkd, o_r[r]);
      }
    }
  }

  #pragma unroll
  for (int r = 0; r < 16; ++r) {
    size_t tok = (size_t)(b * TDIM + qt * 64 + w16 + r);
    y[tok * CDIM + h * HD + lane] = (bf16)(o_r[r] / l_r[r]);
  }
}

// ---------------- launcher ----------------
extern "C" void kernel_launch(void* const* d_in, const int* in_sizes, int n_in,
                              void* d_out, int out_size, void* d_ws, size_t ws_size,
                              hipStream_t stream) {
  (void)in_sizes; (void)n_in; (void)out_size;
  const int*   idx    = (const int*)  d_in[0];
  const float* wte    = (const float*)d_in[1];
  const float* wpe    = (const float*)d_in[2];
  const float* ln1_s  = (const float*)d_in[3];
  const float* ln1_b  = (const float*)d_in[4];
  const float* qkv_w  = (const float*)d_in[5];
  const float* qkv_b  = (const float*)d_in[6];
  const float* proj_w = (const float*)d_in[7];
  const float* proj_b = (const float*)d_in[8];
  const float* ln2_s  = (const float*)d_in[9];
  const float* ln2_b  = (const float*)d_in[10];
  const float* fc_w   = (const float*)d_in[11];
  const float* fc_b   = (const float*)d_in[12];
  const float* fcp_w  = (const float*)d_in[13];
  const float* fcp_b  = (const float*)d_in[14];
  const float* lnf_s  = (const float*)d_in[15];
  const float* lnf_b  = (const float*)d_in[16];
  float* logits = (float*)d_out;

  char* base = (char*)d_ws;
  size_t off = 0;
  auto alloc = [&](size_t bytes) -> void* {
    void* p = base + off;
    off += (bytes + 255) & ~(size_t)255;
    return p;
  };
  bf16*  wte_bf = (bf16*) alloc((size_t)VDIM * CDIM * 2);
  bf16*  wq_t   = (bf16*) alloc((size_t)3 * CDIM * CDIM * 2);
  bf16*  wp_t   = (bf16*) alloc((size_t)CDIM * CDIM * 2);
  bf16*  wf_t   = (bf16*) alloc((size_t)4 * CDIM * CDIM * 2);
  bf16*  wfp_t  = (bf16*) alloc((size_t)4 * CDIM * CDIM * 2);
  float* x      = (float*)alloc((size_t)NTOK * CDIM * 4);
  bf16*  hb     = (bf16*) alloc((size_t)NTOK * CDIM * 2);
  float* qkv    = (float*)alloc((size_t)NTOK * 3 * CDIM * 4);
  bf16*  yb     = (bf16*) alloc((size_t)NTOK * CDIM * 2);
  bf16*  gb     = (bf16*) alloc((size_t)NTOK * 4 * CDIM * 2);
  if (off > ws_size) return;   // ws too small -> clean all-zero failure signature

  k_cvt_bf16<<<4096, 256, 0, stream>>>(wte, wte_bf, (long)VDIM * CDIM);
  k_embed<<<NTOK, 256, 0, stream>>>(idx, wte, wpe, x);

  for (int l = 0; l < LNUM; ++l) {
    // per-layer weight transpose+convert to [N,K] bf16 (reused buffers)
    k_transpose_cvt<<<dim3(3*CDIM/32, CDIM/32), 256, 0, stream>>>(qkv_w + (size_t)l*CDIM*3*CDIM, wq_t, CDIM, 3*CDIM);
    k_transpose_cvt<<<dim3(CDIM/32,   CDIM/32), 256, 0, stream>>>(proj_w + (size_t)l*CDIM*CDIM,  wp_t, CDIM, CDIM);
    k_transpose_cvt<<<dim3(4*CDIM/32, CDIM/32), 256, 0, stream>>>(fc_w  + (size_t)l*CDIM*4*CDIM, wf_t, CDIM, 4*CDIM);
    k_transpose_cvt<<<dim3(CDIM/32, 4*CDIM/32), 256, 0, stream>>>(fcp_w + (size_t)l*4*CDIM*CDIM, wfp_t, 4*CDIM, CDIM);

    k_layernorm<<<NTOK, 256, 0, stream>>>(x, ln1_s + l*CDIM, ln1_b + l*CDIM, hb);
    k_gemm_nt<1><<<dim3(NTOK/BM, 3*CDIM/BN), 256, 0, stream>>>(hb, wq_t, qkv_b + (size_t)l*3*CDIM, nullptr, qkv, nullptr, NTOK, 3*CDIM, CDIM);
    k_attn<<<dim3(BDIM*HNUM, TDIM/64), 256, 0, stream>>>(qkv, yb);
    k_gemm_nt<2><<<dim3(NTOK/BM, CDIM/BN), 256, 0, stream>>>(yb, wp_t, proj_b + (size_t)l*CDIM, x, x, nullptr, NTOK, CDIM, CDIM);
    k_layernorm<<<NTOK, 256, 0, stream>>>(x, ln2_s + l*CDIM, ln2_b + l*CDIM, hb);
    k_gemm_nt<3><<<dim3(NTOK/BM, 4*CDIM/BN), 256, 0, stream>>>(hb, wf_t, fc_b + (size_t)l*4*CDIM, nullptr, nullptr, gb, NTOK, 4*CDIM, CDIM);
    k_gemm_nt<2><<<dim3(NTOK/BM, CDIM/BN), 256, 0, stream>>>(gb, wfp_t, fcp_b + (size_t)l*CDIM, x, x, nullptr, NTOK, CDIM, 4*CDIM);
  }

  k_layernorm<<<NTOK, 256, 0, stream>>>(x, lnf_s, lnf_b, hb);
  int ntile = (VDIM + BN - 1) / BN;  // 393, last tile bounds-guarded
  k_gemm_nt<0><<<dim3(NTOK/BM, ntile), 256, 0, stream>>>(hb, wte_bf, nullptr, nullptr, logits, nullptr, NTOK, VDIM, CDIM);
}

// Round 2
// 2143.038 us; speedup vs baseline: 2.6467x; 2.6467x over previous
//
#include <hip/hip_runtime.h>
#include <math.h>

#define LNUM 6
#define HNUM 12
#define CDIM 768
#define VDIM 50257
#define BDIM 4
#define TDIM 1024
#define NTOK 4096   // B*T

typedef __bf16 bf16;
typedef __bf16 bf16x8 __attribute__((ext_vector_type(8)));
typedef float  floatx4 __attribute__((ext_vector_type(4)));
typedef unsigned int u32;

// async global->LDS, 16B per lane. LDS dest must be wave-uniform base; HW adds lane*16.
__device__ inline void gload16(const bf16* gsrc, bf16* lds) {
  __builtin_amdgcn_global_load_lds(
      (const __attribute__((address_space(1))) u32*)gsrc,
      (__attribute__((address_space(3))) u32*)lds, 16, 0, 0);
}

// ---------------- fp32 -> bf16 bulk convert (wte) ----------------
__global__ void k_cvt_bf16(const float* __restrict__ in, bf16* __restrict__ out, long n) {
  long i = ((long)blockIdx.x * blockDim.x + threadIdx.x) * 4;
  long stride = (long)gridDim.x * blockDim.x * 4;
  for (; i < n; i += stride) {
    float4 v = *reinterpret_cast<const float4*>(in + i);
    bf16 b0 = (bf16)v.x, b1 = (bf16)v.y, b2 = (bf16)v.z, b3 = (bf16)v.w;
    ushort4 pk;
    pk.x = __builtin_bit_cast(unsigned short, b0);
    pk.y = __builtin_bit_cast(unsigned short, b1);
    pk.z = __builtin_bit_cast(unsigned short, b2);
    pk.w = __builtin_bit_cast(unsigned short, b3);
    *reinterpret_cast<ushort4*>(out + i) = pk;
  }
}

// ---------------- transpose + convert: in fp32 [K,N] -> out bf16 [N,K] ----------------
__global__ void k_transpose_cvt(const float* __restrict__ in, bf16* __restrict__ out, int K, int N) {
  __shared__ float tile[32][33];
  int n0 = blockIdx.x * 32, k0 = blockIdx.y * 32;
  int nx = threadIdx.x & 31, ty = threadIdx.x >> 5;
  #pragma unroll
  for (int p = 0; p < 4; ++p) {
    int k = ty + p * 8;
    tile[k][nx] = in[(size_t)(k0 + k) * N + n0 + nx];
  }
  __syncthreads();
  #pragma unroll
  for (int p = 0; p < 4; ++p) {
    int n = ty + p * 8;
    out[(size_t)(n0 + n) * K + k0 + nx] = (bf16)tile[nx][n];
  }
}

// ---------------- embedding ----------------
__global__ void k_embed(const int* __restrict__ idx, const float* __restrict__ wte,
                        const float* __restrict__ wpe, float* __restrict__ x) {
  int tok = blockIdx.x;
  int t = tok & (TDIM - 1);
  int id = idx[tok];
  const float* a = wte + (size_t)id * CDIM;
  const float* p = wpe + (size_t)t * CDIM;
  float* o = x + (size_t)tok * CDIM;
  for (int c = threadIdx.x; c < CDIM; c += 256) o[c] = a[c] + p[c];
}

// ---------------- layernorm: fp32 in -> bf16 out ----------------
__global__ __launch_bounds__(256) void k_layernorm(const float* __restrict__ x,
    const float* __restrict__ sc, const float* __restrict__ bi, bf16* __restrict__ out) {
  __shared__ float red[8];
  int row = blockIdx.x;
  const float* xr = x + (size_t)row * CDIM;
  int t = threadIdx.x;
  float v0 = xr[t], v1 = xr[t + 256], v2 = xr[t + 512];
  float s = v0 + v1 + v2;
  #pragma unroll
  for (int o = 32; o > 0; o >>= 1) s += __shfl_down(s, o);
  if ((t & 63) == 0) red[t >> 6] = s;
  __syncthreads();
  float mean = (red[0] + red[1] + red[2] + red[3]) * (1.0f / CDIM);
  float d0 = v0 - mean, d1 = v1 - mean, d2 = v2 - mean;
  float q = d0 * d0 + d1 * d1 + d2 * d2;
  #pragma unroll
  for (int o = 32; o > 0; o >>= 1) q += __shfl_down(q, o);
  if ((t & 63) == 0) red[4 + (t >> 6)] = q;
  __syncthreads();
  float var = (red[4] + red[5] + red[6] + red[7]) * (1.0f / CDIM);
  float rs = rsqrtf(var + 1e-5f);
  bf16* orow = out + (size_t)row * CDIM;
  orow[t]       = (bf16)(d0 * rs * sc[t]       + bi[t]);
  orow[t + 256] = (bf16)(d1 * rs * sc[t + 256] + bi[t + 256]);
  orow[t + 512] = (bf16)(d2 * rs * sc[t + 512] + bi[t + 512]);
}

__device__ inline float gelu_f(float x) {
  float x3 = x * x * x;
  return 0.5f * x * (1.0f + tanhf(0.7978845608028654f * (x + 0.044715f * x3)));
}

// ---------------- m97-style NT bf16 MFMA GEMM ----------------
// C[M,N] = A[M,K] * Bt[N,K]^T.  BN=128, BK=64, 256 threads (4 waves).
// global_load_lds (16B) staging into linear LDS [rows][64].
// EPI: 0 ->f32, 2 +bias+resid ->f32 (in-place), 3 +bias+gelu ->bf16, 4 +bias ->bf16
template<int TBM, int MI, int NI, int EPI>
__global__ __launch_bounds__(256) void k_gemm(
    const bf16* __restrict__ A, const bf16* __restrict__ Bt,
    const float* __restrict__ bias, const float* __restrict__ resid,
    float* __restrict__ Cf, bf16* __restrict__ Cb,
    int M, int N, int K) {
  constexpr int BN = 128;
  constexpr int WGN = BN / (NI * 16);     // waves along N
  constexpr int AI = TBM / 32;            // gload instrs per wave for A
  constexpr int BI = BN / 32;             // for B
  __shared__ __align__(16) bf16 As[TBM * 64];
  __shared__ __align__(16) bf16 Bs[BN * 64];
  const int m0 = blockIdx.x * TBM, n0 = blockIdx.y * BN;
  const int tid = threadIdx.x;
  const int lane = tid & 63, wave = tid >> 6;
  const int wr = wave / WGN, wc = wave % WGN;
  const int l8 = lane >> 3, s8 = lane & 7;
  const int g = lane >> 4, r16 = lane & 15;

  floatx4 acc[MI][NI] = {};

  const bf16* a_src = A + (size_t)(m0 + l8) * K + s8 * 8;
  const bf16* b_src = Bt + (size_t)(n0 + l8) * K + s8 * 8;

  for (int k0 = 0; k0 < K; k0 += 64) {
    #pragma unroll
    for (int t = 0; t < AI; ++t) {
      int row0 = wave * (TBM / 4) + t * 8;
      gload16(a_src + (size_t)row0 * K + k0, &As[row0 * 64]);
    }
    #pragma unroll
    for (int t = 0; t < BI; ++t) {
      int row0 = wave * 32 + t * 8;
      gload16(b_src + (size_t)row0 * K + k0, &Bs[row0 * 64]);
    }
    __syncthreads();
    #pragma unroll
    for (int kk = 0; kk < 2; ++kk) {
      bf16x8 af[MI], bfr[NI];
      #pragma unroll
      for (int i = 0; i < MI; ++i)
        af[i] = *reinterpret_cast<const bf16x8*>(&As[(wr * MI * 16 + i * 16 + r16) * 64 + g * 8 + kk * 32]);
      #pragma unroll
      for (int j = 0; j < NI; ++j)
        bfr[j] = *reinterpret_cast<const bf16x8*>(&Bs[(wc * NI * 16 + j * 16 + r16) * 64 + g * 8 + kk * 32]);
      #pragma unroll
      for (int i = 0; i < MI; ++i) {
        #pragma unroll
        for (int j = 0; j < NI; ++j)
          acc[i][j] = __builtin_amdgcn_mfma_f32_16x16x32_bf16(af[i], bfr[j], acc[i][j], 0, 0, 0);
      }
    }
    __syncthreads();
  }

  // C/D layout: col = lane&15, row = (lane>>4)*4 + reg
  int mb = m0 + wr * MI * 16 + g * 4;
  int nb = n0 + wc * NI * 16 + r16;
  #pragma unroll
  for (int j = 0; j < NI; ++j) {
    int n = nb + j * 16;
    if (n >= N) continue;
    float bv = (EPI >= 2) ? bias[n] : 0.0f;
    #pragma unroll
    for (int i = 0; i < MI; ++i) {
      #pragma unroll
      for (int q = 0; q < 4; ++q) {
        int m = mb + i * 16 + q;
        float v = acc[i][j][q] + bv;
        size_t o = (size_t)m * N + n;
        if (EPI == 2)      Cf[o] = v + resid[o];
        else if (EPI == 3) Cb[o] = (bf16)gelu_f(v);
        else if (EPI == 4) Cb[o] = (bf16)v;
        else               Cf[o] = v;
      }
    }
  }
}

// ---------------- V transpose: qkv_bf V-part -> vt[bh][d][t] bf16 ----------------
__global__ __launch_bounds__(256) void k_vtrans(const bf16* __restrict__ qkv, bf16* __restrict__ vt) {
  __shared__ bf16 tile[64][72];
  int bh = blockIdx.x, t0 = blockIdx.y * 64;
  int b = bh / HNUM, h = bh % HNUM;
  int tid = threadIdx.x;
  int r8 = tid >> 3, s8 = tid & 7;
  #pragma unroll
  for (int p = 0; p < 2; ++p) {
    int row = p * 32 + r8;
    uint4 v = *reinterpret_cast<const uint4*>(
        qkv + (size_t)(b * TDIM + t0 + row) * (3 * CDIM) + 2 * CDIM + h * 64 + s8 * 8);
    *reinterpret_cast<uint4*>(&tile[row][s8 * 8]) = v;
  }
  __syncthreads();
  int d = tid >> 2, q4 = tid & 3;
  #pragma unroll
  for (int half = 0; half < 2; ++half) {
    int t = q4 * 16 + half * 8;
    bf16x8 o;
    #pragma unroll
    for (int u = 0; u < 8; ++u) o[u] = tile[t + u][d];
    *reinterpret_cast<bf16x8*>(vt + (size_t)bh * (64 * TDIM) + (size_t)d * TDIM + t0 + t) = o;
  }
}

// ---------------- MFMA flash attention ----------------
// grid (B*H, T/64); 256 threads (4 waves); wave owns 16 q rows.
// Q frags in regs; K, Vt staged to XOR-swizzled LDS; P through wave-private LDS rows.
__global__ __launch_bounds__(256) void k_attn(const bf16* __restrict__ qkv,
                                              const bf16* __restrict__ vt,
                                              bf16* __restrict__ y) {
  __shared__ __align__(16) bf16 Ks[64 * 64];
  __shared__ __align__(16) bf16 Vs[64 * 64];
  __shared__ __align__(16) bf16 Ps[64 * 64];
  const int bh = blockIdx.x, qt = blockIdx.y;
  const int b = bh / HNUM, h = bh % HNUM;
  const int tid = threadIdx.x, lane = tid & 63, wave = tid >> 6;
  const int g = lane >> 4, r16 = lane & 15;
  const int w16 = wave * 16;
  const int r8 = tid >> 3, s8 = tid & 7;

  // Q fragments: A-frag rows w16+r16, contraction d = g*8 + c*32
  bf16x8 qf[2];
  {
    const bf16* qsrc = qkv + (size_t)(b * TDIM + qt * 64 + w16 + r16) * (3 * CDIM) + h * 64 + g * 8;
    qf[0] = *reinterpret_cast<const bf16x8*>(qsrc);
    qf[1] = *reinterpret_cast<const bf16x8*>(qsrc + 32);
  }

  float m_r[4], l_r[4];
  floatx4 yacc[4] = {};   // yacc[j][q]: row w16+g*4+q, col d = r16 + j*16
  #pragma unroll
  for (int q = 0; q < 4; ++q) { m_r[q] = -1e30f; l_r[q] = 0.f; }

  for (int kt = 0; kt <= qt; ++kt) {
    __syncthreads();   // prior-iteration readers done before restaging
    #pragma unroll
    for (int p = 0; p < 2; ++p) {
      int row = p * 32 + r8;
      uint4 kv = *reinterpret_cast<const uint4*>(
          qkv + (size_t)(b * TDIM + kt * 64 + row) * (3 * CDIM) + CDIM + h * 64 + s8 * 8);
      *reinterpret_cast<uint4*>(&Ks[row * 64 + ((s8 ^ (row & 7)) * 8)]) = kv;
      uint4 vv = *reinterpret_cast<const uint4*>(
          vt + (size_t)bh * (64 * TDIM) + (size_t)row * TDIM + kt * 64 + s8 * 8);
      *reinterpret_cast<uint4*>(&Vs[row * 64 + ((s8 ^ (row & 7)) * 8)]) = vv;
    }
    __syncthreads();

    // S = Q K^T : sa[j][q] -> q row w16+g*4+q, k col r16 + j*16
    floatx4 sa[4] = {};
    #pragma unroll
    for (int c = 0; c < 2; ++c) {
      bf16x8 kf[4];
      #pragma unroll
      for (int j = 0; j < 4; ++j) {
        int krow = j * 16 + r16;
        kf[j] = *reinterpret_cast<const bf16x8*>(&Ks[krow * 64 + (((g + 4 * c) ^ (krow & 7)) * 8)]);
      }
      #pragma unroll
      for (int j = 0; j < 4; ++j)
        sa[j] = __builtin_amdgcn_mfma_f32_16x16x32_bf16(qf[c], kf[j], sa[j], 0, 0, 0);
    }

    const bool diag = (kt == qt);
    float p_v[4][4];
    #pragma unroll
    for (int q = 0; q < 4; ++q) {
      int qrow = w16 + g * 4 + q;
      float mx = -1e30f;
      #pragma unroll
      for (int j = 0; j < 4; ++j) {
        float s = sa[j][q] * 0.125f;
        if (diag && (r16 + j * 16) > qrow) s = -1e30f;
        p_v[j][q] = s;
        mx = fmaxf(mx, s);
      }
      #pragma unroll
      for (int o = 1; o < 16; o <<= 1) mx = fmaxf(mx, __shfl_xor(mx, o));
      float mnew = fmaxf(m_r[q], mx);
      float ps = 0.f;
      #pragma unroll
      for (int j = 0; j < 4; ++j) {
        float p = __expf(p_v[j][q] - mnew);
        p_v[j][q] = p;
        ps += p;
      }
      #pragma unroll
      for (int o = 1; o < 16; o <<= 1) ps += __shfl_xor(ps, o);
      float alpha = __expf(m_r[q] - mnew);
      m_r[q] = mnew;
      l_r[q] = l_r[q] * alpha + ps;
      #pragma unroll
      for (int j = 0; j < 4; ++j) yacc[j][q] *= alpha;
      // write P row to LDS (swizzled); rows are wave-private -> no barrier needed
      #pragma unroll
      for (int j = 0; j < 4; ++j) {
        int col = r16 + j * 16;
        Ps[qrow * 64 + (col ^ ((qrow & 7) << 3))] = (bf16)p_v[j][q];
      }
    }

    // PV: A = P rows (this wave's), B = Vs rows (d), contraction k = g*8 + ks*32
    #pragma unroll
    for (int ks = 0; ks < 2; ++ks) {
      int prow = w16 + r16;
      bf16x8 pa = *reinterpret_cast<const bf16x8*>(&Ps[prow * 64 + (((g + 4 * ks) ^ (prow & 7)) * 8)]);
      #pragma unroll
      for (int j = 0; j < 4; ++j) {
        int vrow = j * 16 + r16;
        bf16x8 vb = *reinterpret_cast<const bf16x8*>(&Vs[vrow * 64 + (((g + 4 * ks) ^ (vrow & 7)) * 8)]);
        yacc[j] = __builtin_amdgcn_mfma_f32_16x16x32_bf16(pa, vb, yacc[j], 0, 0, 0);
      }
    }
  }

  #pragma unroll
  for (int q = 0; q < 4; ++q) {
    float inv = 1.0f / l_r[q];
    int tok = b * TDIM + qt * 64 + w16 + g * 4 + q;
    #pragma unroll
    for (int j = 0; j < 4; ++j)
      y[(size_t)tok * CDIM + h * 64 + r16 + j * 16] = (bf16)(yacc[j][q] * inv);
  }
}

// ---------------- launcher ----------------
extern "C" void kernel_launch(void* const* d_in, const int* in_sizes, int n_in,
                              void* d_out, int out_size, void* d_ws, size_t ws_size,
                              hipStream_t stream) {
  (void)in_sizes; (void)n_in; (void)out_size;
  const int*   idx    = (const int*)  d_in[0];
  const float* wte    = (const float*)d_in[1];
  const float* wpe    = (const float*)d_in[2];
  const float* ln1_s  = (const float*)d_in[3];
  const float* ln1_b  = (const float*)d_in[4];
  const float* qkv_w  = (const float*)d_in[5];
  const float* qkv_b  = (const float*)d_in[6];
  const float* proj_w = (const float*)d_in[7];
  const float* proj_b = (const float*)d_in[8];
  const float* ln2_s  = (const float*)d_in[9];
  const float* ln2_b  = (const float*)d_in[10];
  const float* fc_w   = (const float*)d_in[11];
  const float* fc_b   = (const float*)d_in[12];
  const float* fcp_w  = (const float*)d_in[13];
  const float* fcp_b  = (const float*)d_in[14];
  const float* lnf_s  = (const float*)d_in[15];
  const float* lnf_b  = (const float*)d_in[16];
  float* logits = (float*)d_out;

  char* base = (char*)d_ws;
  size_t off = 0;
  auto alloc = [&](size_t bytes) -> void* {
    void* p = base + off;
    off += (bytes + 255) & ~(size_t)255;
    return p;
  };
  bf16*  wte_bf = (bf16*) alloc((size_t)VDIM * CDIM * 2);   // keep FIRST (logits B-tile tail overreads land in ws)
  bf16*  wq_t   = (bf16*) alloc((size_t)3 * CDIM * CDIM * 2);
  bf16*  wp_t   = (bf16*) alloc((size_t)CDIM * CDIM * 2);
  bf16*  wf_t   = (bf16*) alloc((size_t)4 * CDIM * CDIM * 2);
  bf16*  wfp_t  = (bf16*) alloc((size_t)4 * CDIM * CDIM * 2);
  float* x      = (float*)alloc((size_t)NTOK * CDIM * 4);
  bf16*  hb     = (bf16*) alloc((size_t)NTOK * CDIM * 2);
  bf16*  qkv_bf = (bf16*) alloc((size_t)NTOK * 3 * CDIM * 2);
  bf16*  vt     = (bf16*) alloc((size_t)BDIM * HNUM * 64 * TDIM * 2);
  bf16*  yb     = (bf16*) alloc((size_t)NTOK * CDIM * 2);
  bf16*  gb     = (bf16*) alloc((size_t)NTOK * 4 * CDIM * 2);
  if (off > ws_size) return;

  k_cvt_bf16<<<4096, 256, 0, stream>>>(wte, wte_bf, (long)VDIM * CDIM);
  k_embed<<<NTOK, 256, 0, stream>>>(idx, wte, wpe, x);

  for (int l = 0; l < LNUM; ++l) {
    k_transpose_cvt<<<dim3(3*CDIM/32, CDIM/32), 256, 0, stream>>>(qkv_w + (size_t)l*CDIM*3*CDIM, wq_t, CDIM, 3*CDIM);
    k_transpose_cvt<<<dim3(CDIM/32,   CDIM/32), 256, 0, stream>>>(proj_w + (size_t)l*CDIM*CDIM,  wp_t, CDIM, CDIM);
    k_transpose_cvt<<<dim3(4*CDIM/32, CDIM/32), 256, 0, stream>>>(fc_w  + (size_t)l*CDIM*4*CDIM, wf_t, CDIM, 4*CDIM);
    k_transpose_cvt<<<dim3(CDIM/32, 4*CDIM/32), 256, 0, stream>>>(fcp_w + (size_t)l*4*CDIM*CDIM, wfp_t, 4*CDIM, CDIM);

    k_layernorm<<<NTOK, 256, 0, stream>>>(x, ln1_s + l*CDIM, ln1_b + l*CDIM, hb);
    k_gemm<128,4,4,4><<<dim3(NTOK/128, 18), 256, 0, stream>>>(hb, wq_t, qkv_b + (size_t)l*3*CDIM, nullptr, nullptr, qkv_bf, NTOK, 3*CDIM, CDIM);
    k_vtrans<<<dim3(BDIM*HNUM, TDIM/64), 256, 0, stream>>>(qkv_bf, vt);
    k_attn<<<dim3(BDIM*HNUM, TDIM/64), 256, 0, stream>>>(qkv_bf, vt, yb);
    k_gemm<64,4,2,2><<<dim3(NTOK/64, 6), 256, 0, stream>>>(yb, wp_t, proj_b + (size_t)l*CDIM, x, x, nullptr, NTOK, CDIM, CDIM);
    k_layernorm<<<NTOK, 256, 0, stream>>>(x, ln2_s + l*CDIM, ln2_b + l*CDIM, hb);
    k_gemm<128,4,4,3><<<dim3(NTOK/128, 24), 256, 0, stream>>>(hb, wf_t, fc_b + (size_t)l*4*CDIM, nullptr, nullptr, gb, NTOK, 4*CDIM, CDIM);
    k_gemm<64,4,2,2><<<dim3(NTOK/64, 6), 256, 0, stream>>>(gb, wfp_t, fcp_b + (size_t)l*CDIM, x, x, nullptr, NTOK, CDIM, 4*CDIM);
  }

  k_layernorm<<<NTOK, 256, 0, stream>>>(x, lnf_s, lnf_b, hb);
  int ntile = (VDIM + 127) / 128;  // 393, tail masked in epilogue (staging tail overreads stay inside ws)
  k_gemm<128,4,4,0><<<dim3(NTOK/128, ntile), 256, 0, stream>>>(hb, wte_bf, nullptr, nullptr, logits, nullptr, NTOK, VDIM, CDIM);
}

// Round 3
// 2049.129 us; speedup vs baseline: 2.7680x; 1.0458x over previous
//
#include <hip/hip_runtime.h>
#include <math.h>

#define LNUM 6
#define HNUM 12
#define CDIM 768
#define VDIM 50257
#define BDIM 4
#define TDIM 1024
#define NTOK 4096   // B*T

typedef __bf16 bf16;
typedef __bf16 bf16x8 __attribute__((ext_vector_type(8)));
typedef float  floatx4 __attribute__((ext_vector_type(4)));
typedef unsigned int u32;

// async global->LDS, 16B per lane. LDS dest must be wave-uniform base; HW adds lane*16.
__device__ inline void gload16(const bf16* gsrc, bf16* lds) {
  __builtin_amdgcn_global_load_lds(
      (const __attribute__((address_space(1))) u32*)gsrc,
      (__attribute__((address_space(3))) u32*)lds, 16, 0, 0);
}

// ---------------- fp32 -> bf16 bulk convert (wte) ----------------
__global__ void k_cvt_bf16(const float* __restrict__ in, bf16* __restrict__ out, long n) {
  long i = ((long)blockIdx.x * blockDim.x + threadIdx.x) * 4;
  long stride = (long)gridDim.x * blockDim.x * 4;
  for (; i < n; i += stride) {
    float4 v = *reinterpret_cast<const float4*>(in + i);
    bf16 b0 = (bf16)v.x, b1 = (bf16)v.y, b2 = (bf16)v.z, b3 = (bf16)v.w;
    ushort4 pk;
    pk.x = __builtin_bit_cast(unsigned short, b0);
    pk.y = __builtin_bit_cast(unsigned short, b1);
    pk.z = __builtin_bit_cast(unsigned short, b2);
    pk.w = __builtin_bit_cast(unsigned short, b3);
    *reinterpret_cast<ushort4*>(out + i) = pk;
  }
}

// ---------------- transpose + convert: in fp32 [K,N] -> out bf16 [N,K] ----------------
__global__ void k_transpose_cvt(const float* __restrict__ in, bf16* __restrict__ out, int K, int N) {
  __shared__ float tile[32][33];
  int n0 = blockIdx.x * 32, k0 = blockIdx.y * 32;
  int nx = threadIdx.x & 31, ty = threadIdx.x >> 5;
  #pragma unroll
  for (int p = 0; p < 4; ++p) {
    int k = ty + p * 8;
    tile[k][nx] = in[(size_t)(k0 + k) * N + n0 + nx];
  }
  __syncthreads();
  #pragma unroll
  for (int p = 0; p < 4; ++p) {
    int n = ty + p * 8;
    out[(size_t)(n0 + n) * K + k0 + nx] = (bf16)tile[nx][n];
  }
}

// ---------------- embedding ----------------
__global__ void k_embed(const int* __restrict__ idx, const float* __restrict__ wte,
                        const float* __restrict__ wpe, float* __restrict__ x) {
  int tok = blockIdx.x;
  int t = tok & (TDIM - 1);
  int id = idx[tok];
  const float* a = wte + (size_t)id * CDIM;
  const float* p = wpe + (size_t)t * CDIM;
  float* o = x + (size_t)tok * CDIM;
  for (int c = threadIdx.x; c < CDIM; c += 256) o[c] = a[c] + p[c];
}

// ---------------- layernorm: fp32 in -> bf16 out ----------------
__global__ __launch_bounds__(256) void k_layernorm(const float* __restrict__ x,
    const float* __restrict__ sc, const float* __restrict__ bi, bf16* __restrict__ out) {
  __shared__ float red[8];
  int row = blockIdx.x;
  const float* xr = x + (size_t)row * CDIM;
  int t = threadIdx.x;
  float v0 = xr[t], v1 = xr[t + 256], v2 = xr[t + 512];
  float s = v0 + v1 + v2;
  #pragma unroll
  for (int o = 32; o > 0; o >>= 1) s += __shfl_down(s, o);
  if ((t & 63) == 0) red[t >> 6] = s;
  __syncthreads();
  float mean = (red[0] + red[1] + red[2] + red[3]) * (1.0f / CDIM);
  float d0 = v0 - mean, d1 = v1 - mean, d2 = v2 - mean;
  float q = d0 * d0 + d1 * d1 + d2 * d2;
  #pragma unroll
  for (int o = 32; o > 0; o >>= 1) q += __shfl_down(q, o);
  if ((t & 63) == 0) red[4 + (t >> 6)] = q;
  __syncthreads();
  float var = (red[4] + red[5] + red[6] + red[7]) * (1.0f / CDIM);
  float rs = rsqrtf(var + 1e-5f);
  bf16* orow = out + (size_t)row * CDIM;
  orow[t]       = (bf16)(d0 * rs * sc[t]       + bi[t]);
  orow[t + 256] = (bf16)(d1 * rs * sc[t + 256] + bi[t + 256]);
  orow[t + 512] = (bf16)(d2 * rs * sc[t + 512] + bi[t + 512]);
}

__device__ inline float gelu_f(float x) {
  float x3 = x * x * x;
  return 0.5f * x * (1.0f + tanhf(0.7978845608028654f * (x + 0.044715f * x3)));
}

// ================= 256x256 8-phase MFMA GEMM (T1+T2-layout+T3+T4+T5) =================
// C[4096,N] = A[4096,K] * Bt[N,K]^T.  BM=BN=256, BK=64, 512 threads (8 waves, 2Mx4N).
// LDS: 2 buffers x 4 K-split regions {B0,A0,B1,A1}, each [256 rows][32 cols] bf16 (16KB).
// 64-B region row stride -> fragment ds_read_b128 covers contiguous 1KiB (minimal banking).
// Phase j of tile t: read region j, stage half 4t+7+j (lead-3), 16 MFMA.
// vmcnt(6) once per tile (3 halves in flight); vmcnt(0) for last 2 tiles (prefetch skipped).
// EPI: 0 ->f32 (no bias, N-tail guard), 3 +bias+gelu ->bf16, 4 +bias ->bf16
template<int EPI>
__global__ __launch_bounds__(512, 1) void k_gemm8(
    const bf16* __restrict__ A, const bf16* __restrict__ Bt,
    const float* __restrict__ bias,
    float* __restrict__ Cf, bf16* __restrict__ Cb,
    int N, int K) {
  __shared__ __align__(16) bf16 lds[2][4][8192];
  const int nwg = gridDim.x;                      // divisible by 8 (M-tiles = 16)
  const int id = blockIdx.x;
  const int swz = (id & 7) * (nwg >> 3) + (id >> 3);   // XCD-chunked (bijective, nwg%8==0)
  const int m0 = (swz & 15) * 256;
  const int n0 = (swz >> 4) * 256;
  const int tid = threadIdx.x, lane = tid & 63, wave = tid >> 6;
  const int wr = wave >> 2, wc = wave & 3;        // wave grid 2(M) x 4(N)
  const int g = lane >> 4, r16 = lane & 15;
  const int numK = K >> 6;

  // staging: wave covers rows wave*16+(lane>>2), call c adds 128 rows; lane&3 -> 16B col slot
  const int srow = wave * 16 + (lane >> 2);
  const int scol = (lane & 3) * 8;
  const bf16* aptr0 = A  + (size_t)(m0 + srow) * K + scol;
  const bf16* aptr1 = A  + (size_t)(m0 + srow + 128) * K + scol;
  const bf16* bptr0 = Bt + (size_t)(n0 + srow) * K + scol;
  const bf16* bptr1 = Bt + (size_t)(n0 + srow + 128) * K + scol;
  const int a_off = (wr * 128 + r16) * 32 + g * 8;
  const int b_off = (wc * 64 + r16) * 32 + g * 8;

  floatx4 acc[8][4] = {};

#define STAGE_HALF(H) do {                                                \
    int H_ = (H);                                                         \
    if (H_ < numK * 4) {                                                  \
      int tau_ = H_ >> 2, h_ = H_ & 3;                                    \
      int isA_ = (h_ & 1), kk_ = (h_ >> 1) & 1;                           \
      bf16* dst_ = &lds[tau_ & 1][h_][wave * 512];                        \
      int ko_ = tau_ * 64 + kk_ * 32;                                     \
      gload16((isA_ ? aptr0 : bptr0) + ko_, dst_);                        \
      gload16((isA_ ? aptr1 : bptr1) + ko_, dst_ + 4096);                 \
    } } while (0)

  // prologue: tile0 fully + 3 halves of tile1 (lead 3)
  STAGE_HALF(0); STAGE_HALF(1); STAGE_HALF(2); STAGE_HALF(3);
  STAGE_HALF(4); STAGE_HALF(5); STAGE_HALF(6);
  asm volatile("s_waitcnt vmcnt(6)" ::: "memory");   // tile0 (oldest 8 loads) landed
  __builtin_amdgcn_s_barrier();

  for (int t = 0; t < numK; ++t) {
    const int p = t & 1;
    const int Hb = 4 * t + 7;
    bf16x8 af[4], bfr[4];

    // ---- phase 0: kk=0, mgroup 0 (reads B0=h0, A0=h1) ----
    #pragma unroll
    for (int j = 0; j < 4; ++j) bfr[j] = *(const bf16x8*)&lds[p][0][b_off + j * 512];
    #pragma unroll
    for (int i = 0; i < 4; ++i) af[i] = *(const bf16x8*)&lds[p][1][a_off + i * 512];
    STAGE_HALF(Hb);
    __builtin_amdgcn_s_barrier();
    asm volatile("s_waitcnt lgkmcnt(0)" ::: "memory");
    __builtin_amdgcn_s_setprio(1);
    #pragma unroll
    for (int i = 0; i < 4; ++i)
      #pragma unroll
      for (int j = 0; j < 4; ++j)
        acc[i][j] = __builtin_amdgcn_mfma_f32_16x16x32_bf16(af[i], bfr[j], acc[i][j], 0, 0, 0);
    __builtin_amdgcn_s_setprio(0);
    __builtin_amdgcn_s_barrier();

    // ---- phase 1: kk=0, mgroup 1 (reads A0=h1; B regs reused) ----
    #pragma unroll
    for (int i = 0; i < 4; ++i) af[i] = *(const bf16x8*)&lds[p][1][a_off + (i + 4) * 512];
    STAGE_HALF(Hb + 1);
    __builtin_amdgcn_s_barrier();
    asm volatile("s_waitcnt lgkmcnt(0)" ::: "memory");
    __builtin_amdgcn_s_setprio(1);
    #pragma unroll
    for (int i = 0; i < 4; ++i)
      #pragma unroll
      for (int j = 0; j < 4; ++j)
        acc[i + 4][j] = __builtin_amdgcn_mfma_f32_16x16x32_bf16(af[i], bfr[j], acc[i + 4][j], 0, 0, 0);
    __builtin_amdgcn_s_setprio(0);
    __builtin_amdgcn_s_barrier();

    // ---- phase 2: kk=1, mgroup 0 (reads B1=h2, A1=h3) ----
    #pragma unroll
    for (int j = 0; j < 4; ++j) bfr[j] = *(const bf16x8*)&lds[p][2][b_off + j * 512];
    #pragma unroll
    for (int i = 0; i < 4; ++i) af[i] = *(const bf16x8*)&lds[p][3][a_off + i * 512];
    STAGE_HALF(Hb + 2);
    __builtin_amdgcn_s_barrier();
    asm volatile("s_waitcnt lgkmcnt(0)" ::: "memory");
    __builtin_amdgcn_s_setprio(1);
    #pragma unroll
    for (int i = 0; i < 4; ++i)
      #pragma unroll
      for (int j = 0; j < 4; ++j)
        acc[i][j] = __builtin_amdgcn_mfma_f32_16x16x32_bf16(af[i], bfr[j], acc[i][j], 0, 0, 0);
    __builtin_amdgcn_s_setprio(0);
    __builtin_amdgcn_s_barrier();

    // ---- phase 3: kk=1, mgroup 1 (reads A1=h3; B regs reused) ----
    #pragma unroll
    for (int i = 0; i < 4; ++i) af[i] = *(const bf16x8*)&lds[p][3][a_off + (i + 4) * 512];
    STAGE_HALF(Hb + 3);
    __builtin_amdgcn_s_barrier();
    asm volatile("s_waitcnt lgkmcnt(0)" ::: "memory");
    __builtin_amdgcn_s_setprio(1);
    #pragma unroll
    for (int i = 0; i < 4; ++i)
      #pragma unroll
      for (int j = 0; j < 4; ++j)
        acc[i + 4][j] = __builtin_amdgcn_mfma_f32_16x16x32_bf16(af[i], bfr[j], acc[i + 4][j], 0, 0, 0);
    __builtin_amdgcn_s_setprio(0);
    // tile boundary: next tile's regions must be landed before its phase-0 ds_reads
    if (t + 2 < numK) { asm volatile("s_waitcnt vmcnt(6)" ::: "memory"); }
    else              { asm volatile("s_waitcnt vmcnt(0)" ::: "memory"); }
    __builtin_amdgcn_s_barrier();
  }
#undef STAGE_HALF

  // epilogue. C/D layout: col = lane&15, row = (lane>>4)*4 + reg
  const int mb = m0 + wr * 128 + g * 4;
  const int nb = n0 + wc * 64 + r16;
  #pragma unroll
  for (int nf = 0; nf < 4; ++nf) {
    int n = nb + nf * 16;
    if (EPI == 0 && n >= N) continue;
    float bv = (EPI >= 3) ? bias[n] : 0.0f;
    #pragma unroll
    for (int mf = 0; mf < 8; ++mf) {
      #pragma unroll
      for (int q = 0; q < 4; ++q) {
        int m = mb + mf * 16 + q;
        float v = acc[mf][nf][q] + bv;
        size_t o = (size_t)m * N + n;
        if (EPI == 3)      Cb[o] = (bf16)gelu_f(v);
        else if (EPI == 4) Cb[o] = (bf16)v;
        else               Cf[o] = v;
      }
    }
  }
}

// ---------------- legacy 2-phase NT GEMM (proj / fcp: N=768) ----------------
template<int TBM, int MI, int NI, int EPI>
__global__ __launch_bounds__(256) void k_gemm(
    const bf16* __restrict__ A, const bf16* __restrict__ Bt,
    const float* __restrict__ bias, const float* __restrict__ resid,
    float* __restrict__ Cf, bf16* __restrict__ Cb,
    int M, int N, int K) {
  constexpr int BN = 128;
  constexpr int WGN = BN / (NI * 16);
  constexpr int AI = TBM / 32;
  constexpr int BI = BN / 32;
  __shared__ __align__(16) bf16 As[TBM * 64];
  __shared__ __align__(16) bf16 Bs[BN * 64];
  const int m0 = blockIdx.x * TBM, n0 = blockIdx.y * BN;
  const int tid = threadIdx.x;
  const int lane = tid & 63, wave = tid >> 6;
  const int wr = wave / WGN, wc = wave % WGN;
  const int l8 = lane >> 3, s8 = lane & 7;
  const int g = lane >> 4, r16 = lane & 15;

  floatx4 acc[MI][NI] = {};

  const bf16* a_src = A + (size_t)(m0 + l8) * K + s8 * 8;
  const bf16* b_src = Bt + (size_t)(n0 + l8) * K + s8 * 8;

  for (int k0 = 0; k0 < K; k0 += 64) {
    #pragma unroll
    for (int t = 0; t < AI; ++t) {
      int row0 = wave * (TBM / 4) + t * 8;
      gload16(a_src + (size_t)row0 * K + k0, &As[row0 * 64]);
    }
    #pragma unroll
    for (int t = 0; t < BI; ++t) {
      int row0 = wave * 32 + t * 8;
      gload16(b_src + (size_t)row0 * K + k0, &Bs[row0 * 64]);
    }
    __syncthreads();
    #pragma unroll
    for (int kk = 0; kk < 2; ++kk) {
      bf16x8 af[MI], bfr[NI];
      #pragma unroll
      for (int i = 0; i < MI; ++i)
        af[i] = *reinterpret_cast<const bf16x8*>(&As[(wr * MI * 16 + i * 16 + r16) * 64 + g * 8 + kk * 32]);
      #pragma unroll
      for (int j = 0; j < NI; ++j)
        bfr[j] = *reinterpret_cast<const bf16x8*>(&Bs[(wc * NI * 16 + j * 16 + r16) * 64 + g * 8 + kk * 32]);
      #pragma unroll
      for (int i = 0; i < MI; ++i) {
        #pragma unroll
        for (int j = 0; j < NI; ++j)
          acc[i][j] = __builtin_amdgcn_mfma_f32_16x16x32_bf16(af[i], bfr[j], acc[i][j], 0, 0, 0);
      }
    }
    __syncthreads();
  }

  int mb = m0 + wr * MI * 16 + g * 4;
  int nb = n0 + wc * NI * 16 + r16;
  #pragma unroll
  for (int j = 0; j < NI; ++j) {
    int n = nb + j * 16;
    if (n >= N) continue;
    float bv = (EPI >= 2) ? bias[n] : 0.0f;
    #pragma unroll
    for (int i = 0; i < MI; ++i) {
      #pragma unroll
      for (int q = 0; q < 4; ++q) {
        int m = mb + i * 16 + q;
        float v = acc[i][j][q] + bv;
        size_t o = (size_t)m * N + n;
        if (EPI == 2)      Cf[o] = v + resid[o];
        else if (EPI == 3) Cb[o] = (bf16)gelu_f(v);
        else if (EPI == 4) Cb[o] = (bf16)v;
        else               Cf[o] = v;
      }
    }
  }
}

// ---------------- V transpose: qkv_bf V-part -> vt[bh][d][t] bf16 ----------------
__global__ __launch_bounds__(256) void k_vtrans(const bf16* __restrict__ qkv, bf16* __restrict__ vt) {
  __shared__ bf16 tile[64][72];
  int bh = blockIdx.x, t0 = blockIdx.y * 64;
  int b = bh / HNUM, h = bh % HNUM;
  int tid = threadIdx.x;
  int r8 = tid >> 3, s8 = tid & 7;
  #pragma unroll
  for (int p = 0; p < 2; ++p) {
    int row = p * 32 + r8;
    uint4 v = *reinterpret_cast<const uint4*>(
        qkv + (size_t)(b * TDIM + t0 + row) * (3 * CDIM) + 2 * CDIM + h * 64 + s8 * 8);
    *reinterpret_cast<uint4*>(&tile[row][s8 * 8]) = v;
  }
  __syncthreads();
  int d = tid >> 2, q4 = tid & 3;
  #pragma unroll
  for (int half = 0; half < 2; ++half) {
    int t = q4 * 16 + half * 8;
    bf16x8 o;
    #pragma unroll
    for (int u = 0; u < 8; ++u) o[u] = tile[t + u][d];
    *reinterpret_cast<bf16x8*>(vt + (size_t)bh * (64 * TDIM) + (size_t)d * TDIM + t0 + t) = o;
  }
}

// ---------------- MFMA flash attention ----------------
__global__ __launch_bounds__(256) void k_attn(const bf16* __restrict__ qkv,
                                              const bf16* __restrict__ vt,
                                              bf16* __restrict__ y) {
  __shared__ __align__(16) bf16 Ks[64 * 64];
  __shared__ __align__(16) bf16 Vs[64 * 64];
  __shared__ __align__(16) bf16 Ps[64 * 64];
  const int bh = blockIdx.x, qt = blockIdx.y;
  const int b = bh / HNUM, h = bh % HNUM;
  const int tid = threadIdx.x, lane = tid & 63, wave = tid >> 6;
  const int g = lane >> 4, r16 = lane & 15;
  const int w16 = wave * 16;
  const int r8 = tid >> 3, s8 = tid & 7;

  bf16x8 qf[2];
  {
    const bf16* qsrc = qkv + (size_t)(b * TDIM + qt * 64 + w16 + r16) * (3 * CDIM) + h * 64 + g * 8;
    qf[0] = *reinterpret_cast<const bf16x8*>(qsrc);
    qf[1] = *reinterpret_cast<const bf16x8*>(qsrc + 32);
  }

  float m_r[4], l_r[4];
  floatx4 yacc[4] = {};
  #pragma unroll
  for (int q = 0; q < 4; ++q) { m_r[q] = -1e30f; l_r[q] = 0.f; }

  for (int kt = 0; kt <= qt; ++kt) {
    __syncthreads();
    #pragma unroll
    for (int p = 0; p < 2; ++p) {
      int row = p * 32 + r8;
      uint4 kv = *reinterpret_cast<const uint4*>(
          qkv + (size_t)(b * TDIM + kt * 64 + row) * (3 * CDIM) + CDIM + h * 64 + s8 * 8);
      *reinterpret_cast<uint4*>(&Ks[row * 64 + ((s8 ^ (row & 7)) * 8)]) = kv;
      uint4 vv = *reinterpret_cast<const uint4*>(
          vt + (size_t)bh * (64 * TDIM) + (size_t)row * TDIM + kt * 64 + s8 * 8);
      *reinterpret_cast<uint4*>(&Vs[row * 64 + ((s8 ^ (row & 7)) * 8)]) = vv;
    }
    __syncthreads();

    floatx4 sa[4] = {};
    #pragma unroll
    for (int c = 0; c < 2; ++c) {
      bf16x8 kf[4];
      #pragma unroll
      for (int j = 0; j < 4; ++j) {
        int krow = j * 16 + r16;
        kf[j] = *reinterpret_cast<const bf16x8*>(&Ks[krow * 64 + (((g + 4 * c) ^ (krow & 7)) * 8)]);
      }
      #pragma unroll
      for (int j = 0; j < 4; ++j)
        sa[j] = __builtin_amdgcn_mfma_f32_16x16x32_bf16(qf[c], kf[j], sa[j], 0, 0, 0);
    }

    const bool diag = (kt == qt);
    float p_v[4][4];
    #pragma unroll
    for (int q = 0; q < 4; ++q) {
      int qrow = w16 + g * 4 + q;
      float mx = -1e30f;
      #pragma unroll
      for (int j = 0; j < 4; ++j) {
        float s = sa[j][q] * 0.125f;
        if (diag && (r16 + j * 16) > qrow) s = -1e30f;
        p_v[j][q] = s;
        mx = fmaxf(mx, s);
      }
      #pragma unroll
      for (int o = 1; o < 16; o <<= 1) mx = fmaxf(mx, __shfl_xor(mx, o));
      float mnew = fmaxf(m_r[q], mx);
      float ps = 0.f;
      #pragma unroll
      for (int j = 0; j < 4; ++j) {
        float p = __expf(p_v[j][q] - mnew);
        p_v[j][q] = p;
        ps += p;
      }
      #pragma unroll
      for (int o = 1; o < 16; o <<= 1) ps += __shfl_xor(ps, o);
      float alpha = __expf(m_r[q] - mnew);
      m_r[q] = mnew;
      l_r[q] = l_r[q] * alpha + ps;
      #pragma unroll
      for (int j = 0; j < 4; ++j) yacc[j][q] *= alpha;
      #pragma unroll
      for (int j = 0; j < 4; ++j) {
        int col = r16 + j * 16;
        Ps[qrow * 64 + (col ^ ((qrow & 7) << 3))] = (bf16)p_v[j][q];
      }
    }

    #pragma unroll
    for (int ks = 0; ks < 2; ++ks) {
      int prow = w16 + r16;
      bf16x8 pa = *reinterpret_cast<const bf16x8*>(&Ps[prow * 64 + (((g + 4 * ks) ^ (prow & 7)) * 8)]);
      #pragma unroll
      for (int j = 0; j < 4; ++j) {
        int vrow = j * 16 + r16;
        bf16x8 vb = *reinterpret_cast<const bf16x8*>(&Vs[vrow * 64 + (((g + 4 * ks) ^ (vrow & 7)) * 8)]);
        yacc[j] = __builtin_amdgcn_mfma_f32_16x16x32_bf16(pa, vb, yacc[j], 0, 0, 0);
      }
    }
  }

  #pragma unroll
  for (int q = 0; q < 4; ++q) {
    float inv = 1.0f / l_r[q];
    int tok = b * TDIM + qt * 64 + w16 + g * 4 + q;
    #pragma unroll
    for (int j = 0; j < 4; ++j)
      y[(size_t)tok * CDIM + h * 64 + r16 + j * 16] = (bf16)(yacc[j][q] * inv);
  }
}

// ---------------- launcher ----------------
extern "C" void kernel_launch(void* const* d_in, const int* in_sizes, int n_in,
                              void* d_out, int out_size, void* d_ws, size_t ws_size,
                              hipStream_t stream) {
  (void)in_sizes; (void)n_in; (void)out_size;
  const int*   idx    = (const int*)  d_in[0];
  const float* wte    = (const float*)d_in[1];
  const float* wpe    = (const float*)d_in[2];
  const float* ln1_s  = (const float*)d_in[3];
  const float* ln1_b  = (const float*)d_in[4];
  const float* qkv_w  = (const float*)d_in[5];
  const float* qkv_b  = (const float*)d_in[6];
  const float* proj_w = (const float*)d_in[7];
  const float* proj_b = (const float*)d_in[8];
  const float* ln2_s  = (const float*)d_in[9];
  const float* ln2_b  = (const float*)d_in[10];
  const float* fc_w   = (const float*)d_in[11];
  const float* fc_b   = (const float*)d_in[12];
  const float* fcp_w  = (const float*)d_in[13];
  const float* fcp_b  = (const float*)d_in[14];
  const float* lnf_s  = (const float*)d_in[15];
  const float* lnf_b  = (const float*)d_in[16];
  float* logits = (float*)d_out;

  char* base = (char*)d_ws;
  size_t off = 0;
  auto alloc = [&](size_t bytes) -> void* {
    void* p = base + off;
    off += (bytes + 255) & ~(size_t)255;
    return p;
  };
  bf16*  wte_bf = (bf16*) alloc((size_t)VDIM * CDIM * 2);   // keep FIRST (logits B-tile tail overreads land in ws)
  bf16*  wq_t   = (bf16*) alloc((size_t)3 * CDIM * CDIM * 2);
  bf16*  wp_t   = (bf16*) alloc((size_t)CDIM * CDIM * 2);
  bf16*  wf_t   = (bf16*) alloc((size_t)4 * CDIM * CDIM * 2);
  bf16*  wfp_t  = (bf16*) alloc((size_t)4 * CDIM * CDIM * 2);
  float* x      = (float*)alloc((size_t)NTOK * CDIM * 4);
  bf16*  hb     = (bf16*) alloc((size_t)NTOK * CDIM * 2);
  bf16*  qkv_bf = (bf16*) alloc((size_t)NTOK * 3 * CDIM * 2);
  bf16*  vt     = (bf16*) alloc((size_t)BDIM * HNUM * 64 * TDIM * 2);
  bf16*  yb     = (bf16*) alloc((size_t)NTOK * CDIM * 2);
  bf16*  gb     = (bf16*) alloc((size_t)NTOK * 4 * CDIM * 2);
  if (off > ws_size) return;

  k_cvt_bf16<<<4096, 256, 0, stream>>>(wte, wte_bf, (long)VDIM * CDIM);
  k_embed<<<NTOK, 256, 0, stream>>>(idx, wte, wpe, x);

  for (int l = 0; l < LNUM; ++l) {
    k_transpose_cvt<<<dim3(3*CDIM/32, CDIM/32), 256, 0, stream>>>(qkv_w + (size_t)l*CDIM*3*CDIM, wq_t, CDIM, 3*CDIM);
    k_transpose_cvt<<<dim3(CDIM/32,   CDIM/32), 256, 0, stream>>>(proj_w + (size_t)l*CDIM*CDIM,  wp_t, CDIM, CDIM);
    k_transpose_cvt<<<dim3(4*CDIM/32, CDIM/32), 256, 0, stream>>>(fc_w  + (size_t)l*CDIM*4*CDIM, wf_t, CDIM, 4*CDIM);
    k_transpose_cvt<<<dim3(CDIM/32, 4*CDIM/32), 256, 0, stream>>>(fcp_w + (size_t)l*4*CDIM*CDIM, wfp_t, 4*CDIM, CDIM);

    k_layernorm<<<NTOK, 256, 0, stream>>>(x, ln1_s + l*CDIM, ln1_b + l*CDIM, hb);
    k_gemm8<4><<<16 * 9, 512, 0, stream>>>(hb, wq_t, qkv_b + (size_t)l*3*CDIM, nullptr, qkv_bf, 3*CDIM, CDIM);
    k_vtrans<<<dim3(BDIM*HNUM, TDIM/64), 256, 0, stream>>>(qkv_bf, vt);
    k_attn<<<dim3(BDIM*HNUM, TDIM/64), 256, 0, stream>>>(qkv_bf, vt, yb);
    k_gemm<64,4,2,2><<<dim3(NTOK/64, 6), 256, 0, stream>>>(yb, wp_t, proj_b + (size_t)l*CDIM, x, x, nullptr, NTOK, CDIM, CDIM);
    k_layernorm<<<NTOK, 256, 0, stream>>>(x, ln2_s + l*CDIM, ln2_b + l*CDIM, hb);
    k_gemm8<3><<<16 * 12, 512, 0, stream>>>(hb, wf_t, fc_b + (size_t)l*4*CDIM, nullptr, gb, 4*CDIM, CDIM);
    k_gemm<64,4,2,2><<<dim3(NTOK/64, 6), 256, 0, stream>>>(gb, wfp_t, fcp_b + (size_t)l*CDIM, x, x, nullptr, NTOK, CDIM, 4*CDIM);
  }

  k_layernorm<<<NTOK, 256, 0, stream>>>(x, lnf_s, lnf_b, hb);
  int ntile = (VDIM + 255) / 256;  // 197; tail masked in epilogue, staging overreads stay in ws
  k_gemm8<0><<<16 * ntile, 512, 0, stream>>>(hb, wte_bf, nullptr, logits, nullptr, VDIM, CDIM);
}